// Round 10
// baseline (168.488 us; speedup 1.0000x reference)
//
#include <hip/hip_runtime.h>
#include <hip/hip_bf16.h>

namespace {
constexpr int kB   = 4;
constexpr int kL   = 2048;
constexpr int kLc  = 2051;   // L + 3
constexpr int kD   = 1024;
constexpr int kS   = 64;
constexpr int kM   = kB * kLc;  // 8204
constexpr int kNR  = 256;       // raw row stride (196 real cols)
constexpr int kQ   = 32;        // chunk length
constexpr int kTC  = (kLc + kQ - 1) / kQ;  // 65 chunks per batch
constexpr int kGA  = 514;       // A groups of 16 rows (8224 padded rows)
constexpr int kGT  = 16384;     // u16 per 16-row group (16*1024)
}

typedef __attribute__((ext_vector_type(8))) short bf16x8;
typedef __attribute__((ext_vector_type(4))) float f32x4;
typedef __attribute__((ext_vector_type(8))) unsigned short u16x8;

__device__ __forceinline__ float siluf_(float v) {
  return v / (1.f + expf(-v));
}
__device__ __forceinline__ float softplusf_(float v) {
  return (v > 20.f) ? v : log1pf(expf(v));
}
__device__ __forceinline__ unsigned short f2bf_(float f) {
  unsigned u = __float_as_uint(f);
  unsigned r = u + 0x7FFF + ((u >> 16) & 1);
  return (unsigned short)(r >> 16);
}
__device__ __forceinline__ float bf2f_(unsigned short u) {
  return __uint_as_float(((unsigned)u) << 16);
}

// ---------------- K1: depthwise conv1d -> xcp (packed) + xT (transposed) --
__global__ __launch_bounds__(256) void conv_kernel(
    const float* __restrict__ x, const float* __restrict__ cw,
    const float* __restrict__ cb, unsigned short* __restrict__ xcp,
    unsigned short* __restrict__ xT) {
  int idx = blockIdx.x * blockDim.x + threadIdx.x;
  const int D4 = kD / 4;
  if (idx >= kB * kLc * D4) return;
  int d4 = idx % D4;
  int bt = idx / D4;
  int t = bt % kLc;
  int b = bt / kLc;
  int d = d4 * 4;

  float4 w0 = *(const float4*)(cw + (size_t)(d + 0) * 4);
  float4 w1 = *(const float4*)(cw + (size_t)(d + 1) * 4);
  float4 w2 = *(const float4*)(cw + (size_t)(d + 2) * 4);
  float4 w3 = *(const float4*)(cw + (size_t)(d + 3) * 4);
  float4 acc = *(const float4*)(cb + d);

#pragma unroll
  for (int k = 0; k < 4; ++k) {
    int ti = t + k - 3;
    if (ti >= 0 && ti < kL) {
      float4 xv = *(const float4*)(x + ((size_t)b * kL + ti) * kD + d);
      acc.x = fmaf(((const float*)&w0)[k], xv.x, acc.x);
      acc.y = fmaf(((const float*)&w1)[k], xv.y, acc.y);
      acc.z = fmaf(((const float*)&w2)[k], xv.z, acc.z);
      acc.w = fmaf(((const float*)&w3)[k], xv.w, acc.w);
    }
  }
  ushort4 bv;
  bv.x = f2bf_(acc.x);
  bv.y = f2bf_(acc.y);
  bv.z = f2bf_(acc.z);
  bv.w = f2bf_(acc.w);
  // packed A layout: [g][kt][r][k&31], g=bt>>4, r=bt&15
  {
    size_t po = (size_t)(bt >> 4) * kGT + (size_t)(d >> 5) * 512 +
                (size_t)(bt & 15) * 32 + (d & 31);
    *(ushort4*)(xcp + po) = bv;
  }
  // transposed layout: [bc][d][tau]
  {
    int c = t >> 5, tau = t & 31;
    size_t xo = ((size_t)(b * kTC + c) * kD + d) * kQ + tau;
    xT[xo + 0 * kQ] = bv.x;
    xT[xo + 1 * kQ] = bv.y;
    xT[xo + 2 * kQ] = bv.z;
    xT[xo + 3 * kQ] = bv.w;
  }
}

// ---------------- K1b: pack Wcat into fragment-tiled bf16 -----------------
// grid (16 groups, 8 k-slabs of 128); block = 16 rows x 16 k8-chunks.
__global__ __launch_bounds__(256) void wcat_kernel(
    const float* __restrict__ W_U, const float* __restrict__ W_B,
    const float* __restrict__ W_C, const float* __restrict__ W_d1,
    unsigned short* __restrict__ wcp) {
  int g = blockIdx.x;
  int kq = blockIdx.y;
  int tid = threadIdx.x;
  int c8 = tid & 15, r = tid >> 4;
  int n = g * 16 + r;
  int k = kq * 128 + c8 * 8;
  const float* src = nullptr;
  if (n < 64)        src = W_U + (size_t)n * kD;
  else if (n < 128)  src = W_B + (size_t)(n - 64) * kD;
  else if (n < 192)  src = W_C + (size_t)(n - 128) * kD;
  else if (n < 196)  src = W_d1 + (size_t)(n - 192) * kD;
  u16x8 o;
#pragma unroll
  for (int j = 0; j < 8; ++j) o[j] = src ? f2bf_(src[k + j]) : (unsigned short)0;
  size_t dst = (size_t)g * kGT + (size_t)(k >> 5) * 512 + r * 32 + (k & 31);
  *(u16x8*)(wcp + dst) = o;
}

// ---------------- K2: raw = xcp @ wcp^T via MFMA (packed, coalesced) ------
__global__ __launch_bounds__(256) void gemm_mfma_kernel(
    const unsigned short* __restrict__ xcp,
    const unsigned short* __restrict__ wcp, float* __restrict__ raw) {
  int tid = threadIdx.x;
  int w = tid >> 6, lane = tid & 63;
  int m0 = blockIdx.x * 32 + (w >> 1) * 16;
  int n0 = blockIdx.y * 128 + (w & 1) * 64;
  int l15 = lane & 15, lk = lane >> 4;

  const unsigned short* ap =
      xcp + (size_t)(blockIdx.x * 2 + (w >> 1)) * kGT + l15 * 32 + lk * 8;
  const unsigned short* bp =
      wcp + (size_t)(blockIdx.y * 8 + (w & 1) * 4) * kGT + l15 * 32 + lk * 8;

  f32x4 acc0 = {0.f, 0.f, 0.f, 0.f}, acc1 = acc0, acc2 = acc0, acc3 = acc0;

  bf16x8 a  = *(const bf16x8*)(ap);
  bf16x8 b0 = *(const bf16x8*)(bp + (size_t)0 * kGT);
  bf16x8 b1 = *(const bf16x8*)(bp + (size_t)1 * kGT);
  bf16x8 b2 = *(const bf16x8*)(bp + (size_t)2 * kGT);
  bf16x8 b3 = *(const bf16x8*)(bp + (size_t)3 * kGT);

#pragma unroll 4
  for (int kt = 1; kt < 32; ++kt) {
    bf16x8 an  = *(const bf16x8*)(ap + kt * 512);
    bf16x8 b0n = *(const bf16x8*)(bp + (size_t)0 * kGT + kt * 512);
    bf16x8 b1n = *(const bf16x8*)(bp + (size_t)1 * kGT + kt * 512);
    bf16x8 b2n = *(const bf16x8*)(bp + (size_t)2 * kGT + kt * 512);
    bf16x8 b3n = *(const bf16x8*)(bp + (size_t)3 * kGT + kt * 512);
    acc0 = __builtin_amdgcn_mfma_f32_16x16x32_bf16(a, b0, acc0, 0, 0, 0);
    acc1 = __builtin_amdgcn_mfma_f32_16x16x32_bf16(a, b1, acc1, 0, 0, 0);
    acc2 = __builtin_amdgcn_mfma_f32_16x16x32_bf16(a, b2, acc2, 0, 0, 0);
    acc3 = __builtin_amdgcn_mfma_f32_16x16x32_bf16(a, b3, acc3, 0, 0, 0);
    a = an; b0 = b0n; b1 = b1n; b2 = b2n; b3 = b3n;
  }
  acc0 = __builtin_amdgcn_mfma_f32_16x16x32_bf16(a, b0, acc0, 0, 0, 0);
  acc1 = __builtin_amdgcn_mfma_f32_16x16x32_bf16(a, b1, acc1, 0, 0, 0);
  acc2 = __builtin_amdgcn_mfma_f32_16x16x32_bf16(a, b2, acc2, 0, 0, 0);
  acc3 = __builtin_amdgcn_mfma_f32_16x16x32_bf16(a, b3, acc3, 0, 0, 0);

  int crow0 = m0 + lk * 4;
  f32x4 accs[4] = {acc0, acc1, acc2, acc3};
#pragma unroll
  for (int nf = 0; nf < 4; ++nf) {
    int col = n0 + nf * 16 + l15;
#pragma unroll
    for (int r = 0; r < 4; ++r) {
      int row = crow0 + r;
      if (row < kM) raw[(size_t)row * kNR + col] = accs[nf][r];
    }
  }
}

// ---------------- K3: passA — delta/D, G, C~ (bf16), Bpre (bf16), dec -----
__global__ __launch_bounds__(256) void passA_kernel(
    const float* __restrict__ raw,
    const float* __restrict__ b_B, const float* __restrict__ b_C,
    const float* __restrict__ b_d1, const float* __restrict__ W_d2,
    const float* __restrict__ b_d2, const float* __restrict__ a_hat,
    unsigned short* __restrict__ Gm, unsigned short* __restrict__ Ctb,
    unsigned short* __restrict__ Bpre, float* __restrict__ dec) {
  __shared__ __align__(16) float Cfl[32][68];
  __shared__ __align__(16) float BulT[64][36];
  __shared__ float deltal[32];
  __shared__ float Dloc[32];
  __shared__ float logAl[64];

  int tid = threadIdx.x;
  int bc = blockIdx.x;
  int b = bc / kTC, c = bc % kTC;
  int t0 = c * kQ;
  int clen = min(kQ, kLc - t0);

  if (tid < 64) logAl[tid] = -expf(a_hat[tid]);
  if (tid >= 64 && tid < 96) {
    int t = tid - 64;
    float r0 = 0.f, r1 = 0.f, r2 = 0.f, r3 = 0.f;
    if (t < clen) {
      const float* rp = raw + (size_t)(b * kLc + t0 + t) * kNR + 192;
      r0 = rp[0]; r1 = rp[1]; r2 = rp[2]; r3 = rp[3];
    }
    float f0 = siluf_(r0 + b_d1[0]);
    float f1 = siluf_(r1 + b_d1[1]);
    float f2 = siluf_(r2 + b_d1[2]);
    float f3 = siluf_(r3 + b_d1[3]);
    float z = fmaf(f0, W_d2[0],
              fmaf(f1, W_d2[1], fmaf(f2, W_d2[2], fmaf(f3, W_d2[3], b_d2[0]))));
    deltal[t] = softplusf_(z);
  }
  // Bu / Cf  (pad rows -> u=0 so Bu=0)
  for (int p = 0; p < 8; ++p) {
    int idx = p * 256 + tid;
    int t = idx >> 6, s = idx & 63;
    float u = 0.f, rb = 0.f, rc = 0.f;
    if (t < clen) {
      const float* rp = raw + (size_t)(b * kLc + t0 + t) * kNR;
      u = rp[s]; rb = rp[64 + s]; rc = rp[128 + s];
    }
    BulT[s][t] = (rb + b_B[s]) * u;
    Cfl[t][s] = rc + b_C[s];
  }
  __syncthreads();
  if (tid < 32) {
    float sum = 0.f;
    for (int j = 0; j <= tid; ++j) sum += deltal[j];
    Dloc[tid] = sum;
  }
  __syncthreads();
  float Dend = Dloc[31];

  // C~ bf16 [t][s]
  for (int p = 0; p < 8; ++p) {
    int idx = p * 256 + tid;
    int t = idx >> 6, s = idx & 63;
    Ctb[(size_t)bc * 2048 + t * kS + s] =
        f2bf_(Cfl[t][s] * __expf(Dloc[t] * logAl[s]));
  }
  // Bpre bf16 [s][tau]
  for (int p = 0; p < 8; ++p) {
    int idx = p * 256 + tid;
    int s = idx >> 5, tau = idx & 31;
    Bpre[(size_t)bc * 2048 + s * kQ + tau] =
        f2bf_(BulT[s][tau] * __expf((Dend - Dloc[tau]) * logAl[s]));
  }
  if (tid < 64) dec[(size_t)bc * kS + tid] = __expf(Dend * logAl[tid]);
  // G[t][tau] lower-triangular, bf16
  for (int p = 0; p < 4; ++p) {
    int idx = p * 256 + tid;
    int t = idx >> 5, tau = idx & 31;
    float g = 0.f;
    if (tau <= t) {
      float dd = Dloc[t] - Dloc[tau];
      for (int s = 0; s < 64; ++s)
        g = fmaf(Cfl[t][s] * BulT[s][tau], __expf(dd * logAl[s]), g);
    }
    Gm[((size_t)bc * 32 + t) * kQ + tau] = f2bf_(g);
  }
}

// ---------------- K3b: ScT[d][s] = x @ Bpre^T via MFMA --------------------
__global__ __launch_bounds__(256) void scT_kernel(
    const unsigned short* __restrict__ Bpre, const unsigned short* __restrict__ xT,
    unsigned short* __restrict__ ScT) {
  __shared__ __align__(16) unsigned short Bprel[64][40];
  int tid = threadIdx.x;
  int bc = blockIdx.x;
  int dq = blockIdx.y;  // 0..3
  {
    int s = tid >> 2, c8 = (tid & 3) * 8;
    *(u16x8*)&Bprel[s][c8] = *(const u16x8*)(Bpre + (size_t)bc * 2048 + s * kQ + c8);
  }
  __syncthreads();
  int w = tid >> 6, lane = tid & 63;
  int l15 = lane & 15, lk = lane >> 4;
  bf16x8 bfr[4];
#pragma unroll
  for (int st = 0; st < 4; ++st)
    bfr[st] = *(const bf16x8*)&Bprel[st * 16 + l15][lk * 8];
  const unsigned short* xTb = xT + (size_t)bc * kD * kQ;
  unsigned short* so = ScT + (size_t)bc * kD * kS;
#pragma unroll
  for (int mt = 0; mt < 4; ++mt) {
    int d0t = dq * 256 + (w * 4 + mt) * 16;
    bf16x8 af = *(const bf16x8*)(xTb + (size_t)(d0t + l15) * kQ + lk * 8);
    f32x4 acc[4];
#pragma unroll
    for (int st = 0; st < 4; ++st) {
      f32x4 z = {0.f, 0.f, 0.f, 0.f};
      acc[st] = __builtin_amdgcn_mfma_f32_16x16x32_bf16(af, bfr[st], z, 0, 0, 0);
    }
#pragma unroll
    for (int st = 0; st < 4; ++st)
#pragma unroll
      for (int r = 0; r < 4; ++r)
        so[(size_t)(d0t + lk * 4 + r) * kS + st * 16 + l15] = f2bf_(acc[st][r]);
  }
}

// ---------------- K4: cross-chunk scan on ScT (flat, burst-prefetched) ----
__global__ __launch_bounds__(256) void chscan_kernel(
    const float* __restrict__ dec, unsigned short* __restrict__ Sc) {
  int bk = blockIdx.x >> 7;           // batch
  int part = blockIdx.x & 127;
  int p = part * 256 + threadIdx.x;   // pair index over kS*kD/2
  int flat = p * 2;                   // element index (d*64 + s), s0 even
  int s0 = flat & 63;
  const size_t cstride = (size_t)kS * kD;
  size_t base = (size_t)bk * kTC * cstride + flat;
  const float* decb = dec + (size_t)bk * kTC * kS + s0;
  float r0 = 0.f, r1 = 0.f;
  for (int c0 = 0; c0 < kTC; c0 += 16) {
    int n = kTC - c0;
    if (n > 16) n = 16;
    unsigned v[16];
    float2 dd[16];
#pragma unroll
    for (int j = 0; j < 16; ++j) {
      if (j < n) {
        v[j] = *(const unsigned*)(Sc + base + (size_t)(c0 + j) * cstride);
        dd[j] = *(const float2*)(decb + (size_t)(c0 + j) * kS);
      }
    }
#pragma unroll
    for (int j = 0; j < 16; ++j) {
      if (j < n) {
        unsigned ost = (unsigned)f2bf_(r0) | ((unsigned)f2bf_(r1) << 16);
        *(unsigned*)(Sc + base + (size_t)(c0 + j) * cstride) = ost;  // H_before
        r0 = fmaf(dd[j].x, r0, bf2f_((unsigned short)(v[j] & 0xFFFF)));
        r1 = fmaf(dd[j].y, r1, bf2f_((unsigned short)(v[j] >> 16)));
      }
    }
  }
}

// ---------------- K5: passB — y = G@x + C~@H0 + ds*x, all-MFMA ------------
__global__ __launch_bounds__(256) void passB_kernel(
    const unsigned short* __restrict__ Gm, const unsigned short* __restrict__ Ctb,
    const unsigned short* __restrict__ xT, const unsigned short* __restrict__ hT,
    const float* __restrict__ D_skip, float* __restrict__ out) {
  int tid = threadIdx.x;
  int bc = blockIdx.x;
  int quarter = blockIdx.y;
  int b = bc / kTC, c = bc % kTC;
  int t0c = c * kQ;
  int clen = min(kQ, kLc - t0c);
  int w = tid >> 6, lane = tid & 63;
  int l15 = lane & 15, lk = lane >> 4;

  const unsigned short* Gb = Gm + (size_t)bc * 32 * kQ;
  bf16x8 aG0 = *(const bf16x8*)(Gb + (size_t)l15 * kQ + lk * 8);
  bf16x8 aG1 = *(const bf16x8*)(Gb + (size_t)(16 + l15) * kQ + lk * 8);
  const unsigned short* Cb = Ctb + (size_t)bc * 2048;
  bf16x8 aC0l = *(const bf16x8*)(Cb + (size_t)l15 * kS + lk * 8);
  bf16x8 aC0h = *(const bf16x8*)(Cb + (size_t)l15 * kS + 32 + lk * 8);
  bf16x8 aC1l = *(const bf16x8*)(Cb + (size_t)(16 + l15) * kS + lk * 8);
  bf16x8 aC1h = *(const bf16x8*)(Cb + (size_t)(16 + l15) * kS + 32 + lk * 8);

  const unsigned short* xTb = xT + (size_t)bc * kD * kQ;
  const unsigned short* hTb = hT + (size_t)bc * kD * kS;
  size_t rowbase = (size_t)b * kLc + t0c;
  int dbase = quarter * 256 + w * 64;

#pragma unroll
  for (int nt = 0; nt < 4; ++nt) {
    int d = dbase + nt * 16 + l15;
    bf16x8 bX  = *(const bf16x8*)(xTb + (size_t)d * kQ + lk * 8);
    bf16x8 bHl = *(const bf16x8*)(hTb + (size_t)d * kS + lk * 8);
    bf16x8 bHh = *(const bf16x8*)(hTb + (size_t)d * kS + 32 + lk * 8);
    f32x4 z = {0.f, 0.f, 0.f, 0.f};
    f32x4 accA = __builtin_amdgcn_mfma_f32_16x16x32_bf16(aC0l, bHl, z, 0, 0, 0);
    accA = __builtin_amdgcn_mfma_f32_16x16x32_bf16(aC0h, bHh, accA, 0, 0, 0);
    accA = __builtin_amdgcn_mfma_f32_16x16x32_bf16(aG0, bX, accA, 0, 0, 0);
    f32x4 accB = __builtin_amdgcn_mfma_f32_16x16x32_bf16(aC1l, bHl, z, 0, 0, 0);
    accB = __builtin_amdgcn_mfma_f32_16x16x32_bf16(aC1h, bHh, accB, 0, 0, 0);
    accB = __builtin_amdgcn_mfma_f32_16x16x32_bf16(aG1, bX, accB, 0, 0, 0);

    float ds = D_skip[d];
    ushort4 xa = *(const ushort4*)(xTb + (size_t)d * kQ + lk * 4);
    ushort4 xb = *(const ushort4*)(xTb + (size_t)d * kQ + 16 + lk * 4);
    const unsigned short* xap = (const unsigned short*)&xa;
    const unsigned short* xbp = (const unsigned short*)&xb;
#pragma unroll
    for (int r = 0; r < 4; ++r) {
      int t = lk * 4 + r;
      if (t < clen)
        out[(rowbase + t) * kD + d] = fmaf(ds, bf2f_(xap[r]), accA[r]);
      int t2 = 16 + lk * 4 + r;
      if (t2 < clen)
        out[(rowbase + t2) * kD + d] = fmaf(ds, bf2f_(xbp[r]), accB[r]);
    }
  }
}

extern "C" void kernel_launch(void* const* d_in, const int* in_sizes, int n_in,
                              void* d_out, int out_size, void* d_ws, size_t ws_size,
                              hipStream_t stream) {
  const float* x      = (const float*)d_in[0];
  const float* a_hat  = (const float*)d_in[1];
  const float* W_U    = (const float*)d_in[2];
  const float* W_B    = (const float*)d_in[3];
  const float* b_B    = (const float*)d_in[4];
  const float* W_C    = (const float*)d_in[5];
  const float* b_C    = (const float*)d_in[6];
  const float* W_d1   = (const float*)d_in[7];
  const float* b_d1   = (const float*)d_in[8];
  const float* W_d2   = (const float*)d_in[9];
  const float* b_d2   = (const float*)d_in[10];
  const float* D_skip = (const float*)d_in[11];
  const float* conv_w = (const float*)d_in[12];
  const float* conv_b = (const float*)d_in[13];
  float* out = (float*)d_out;

  char* w = (char*)d_ws;
  auto nextp = [&](size_t bytes) {
    char* p = w;
    w += (bytes + 255) & ~(size_t)255;
    return p;
  };
  unsigned short* xcp  = (unsigned short*)nextp((size_t)kGA * kGT * 2);
  unsigned short* wcp  = (unsigned short*)nextp((size_t)16 * kGT * 2);
  unsigned short* xT   = (unsigned short*)nextp((size_t)kB * kTC * kD * kQ * 2);
  float*          raw  = (float*)nextp((size_t)kM * kNR * 4);
  unsigned short* Gm   = (unsigned short*)nextp((size_t)kB * kTC * 32 * kQ * 2);
  unsigned short* Ctb  = (unsigned short*)nextp((size_t)kB * kTC * 2048 * 2);
  unsigned short* Bpre = (unsigned short*)nextp((size_t)kB * kTC * 2048 * 2);
  float*          dec  = (float*)nextp((size_t)kB * kTC * kS * 4);
  unsigned short* ScT  = (unsigned short*)nextp((size_t)kB * kTC * kD * kS * 2);

  // zero-pad: xcp groups 512..513 (rows >= kM), and xT tail chunk per batch
  hipMemsetAsync(xcp + (size_t)512 * kGT, 0, (size_t)2 * kGT * 2, stream);
  for (int b = 0; b < kB; ++b) {
    size_t off = ((size_t)(b * kTC + (kTC - 1)) * kD) * kQ;
    hipMemsetAsync(xT + off, 0, (size_t)kD * kQ * 2, stream);
  }

  int convThreads = kB * kLc * (kD / 4);
  conv_kernel<<<(convThreads + 255) / 256, 256, 0, stream>>>(x, conv_w, conv_b,
                                                             xcp, xT);

  dim3 wgrid(16, 8);
  wcat_kernel<<<wgrid, 256, 0, stream>>>(W_U, W_B, W_C, W_d1, wcp);

  dim3 ggrid((kM + 31) / 32, 2);
  gemm_mfma_kernel<<<ggrid, 256, 0, stream>>>(xcp, wcp, raw);

  passA_kernel<<<kB * kTC, 256, 0, stream>>>(
      raw, b_B, b_C, b_d1, W_d2, b_d2, a_hat, Gm, Ctb, Bpre, dec);

  dim3 sgrid(kB * kTC, 4);
  scT_kernel<<<sgrid, 256, 0, stream>>>(Bpre, xT, ScT);

  chscan_kernel<<<kB * 128, 256, 0, stream>>>(dec, ScT);

  dim3 bgrid(kB * kTC, 4);
  passB_kernel<<<bgrid, 256, 0, stream>>>(Gm, Ctb, xT, ScT, D_skip, out);
}

// Round 11
// 113.583 us; speedup vs baseline: 1.4834x; 1.4834x over previous
//
#include <hip/hip_runtime.h>
#include <hip/hip_bf16.h>

namespace {
constexpr int kB   = 4;
constexpr int kL   = 2048;
constexpr int kLc  = 2051;   // L + 3
constexpr int kD   = 1024;
constexpr int kS   = 64;
constexpr int kM   = kB * kLc;  // 8204
constexpr int kNR  = 256;       // raw row stride (196 real cols)
constexpr int kQ   = 32;        // chunk length
constexpr int kTC  = (kLc + kQ - 1) / kQ;  // 65 chunks per batch
constexpr int kGA  = 514;       // A groups of 16 rows (8224 padded rows)
constexpr int kGT  = 16384;     // u16 per 16-row group (16*1024)
}

typedef __attribute__((ext_vector_type(8))) short bf16x8;
typedef __attribute__((ext_vector_type(4))) float f32x4;
typedef __attribute__((ext_vector_type(8))) unsigned short u16x8;

__device__ __forceinline__ float siluf_(float v) {
  return v / (1.f + expf(-v));
}
__device__ __forceinline__ float softplusf_(float v) {
  return (v > 20.f) ? v : log1pf(expf(v));
}
__device__ __forceinline__ unsigned short f2bf_(float f) {
  unsigned u = __float_as_uint(f);
  unsigned r = u + 0x7FFF + ((u >> 16) & 1);
  return (unsigned short)(r >> 16);
}
__device__ __forceinline__ float bf2f_(unsigned short u) {
  return __uint_as_float(((unsigned)u) << 16);
}

// ---------------- K1: conv1d tile kernel -> xcp (packed) + xT (LDS xpose) -
// block = (bc, 128-d slab); thread = (tau-half, d-local); 16 steps serial.
__global__ __launch_bounds__(256) void conv_kernel(
    const float* __restrict__ x, const float* __restrict__ cw,
    const float* __restrict__ cb, unsigned short* __restrict__ xcp,
    unsigned short* __restrict__ xT) {
  __shared__ unsigned short tileT[kQ][136];  // [tau][d], pad->4-way max

  int tid = threadIdx.x;
  int bc = blockIdx.x;
  int d0 = blockIdx.y * 128;
  int b = bc / kTC, c = bc % kTC;
  int t0 = c * kQ;
  int dl = tid & 127, tg = tid >> 7;
  int d = d0 + dl;

  float4 wv = *(const float4*)(cw + (size_t)d * 4);
  float bias = cb[d];
  int tstart = t0 + tg * 16;

  const float* xb = x + (size_t)b * kL * kD + d;
  auto ldx = [&](int t) -> float {
    return (t >= 0 && t < kL) ? xb[(size_t)t * kD] : 0.f;
  };
  float xm3 = ldx(tstart - 3);
  float xm2 = ldx(tstart - 2);
  float xm1 = ldx(tstart - 1);

  unsigned short vals[16];
#pragma unroll
  for (int j = 0; j < 16; ++j) {
    int t = tstart + j;
    float x0 = ldx(t);
    float o = bias + wv.x * xm3 + wv.y * xm2 + wv.z * xm1 + wv.w * x0;
    vals[j] = (t < kLc) ? f2bf_(o) : (unsigned short)0;
    tileT[tg * 16 + j][dl] = vals[j];
    xm3 = xm2; xm2 = xm1; xm1 = x0;
  }
  // xcp store from registers: lanes fill whole 64B lines (dense)
#pragma unroll
  for (int j = 0; j < 16; ++j) {
    int t = tstart + j;
    if (t < kLc) {
      int bt = b * kLc + t;
      size_t po = (size_t)(bt >> 4) * kGT + (size_t)(d >> 5) * 512 +
                  (size_t)(bt & 15) * 32 + (d & 31);
      xcp[po] = vals[j];
    }
  }
  __syncthreads();
  // xT store: [bc][d][tau], contiguous 32B per (d, tau-half)
  {
    int d_l = tid >> 1, th = tid & 1;
    u16x8 o0, o1;
#pragma unroll
    for (int j = 0; j < 8; ++j) {
      o0[j] = tileT[th * 16 + j][d_l];
      o1[j] = tileT[th * 16 + 8 + j][d_l];
    }
    unsigned short* dst = xT + ((size_t)bc * kD + d0 + d_l) * kQ + th * 16;
    *(u16x8*)dst = o0;
    *(u16x8*)(dst + 8) = o1;
  }
}

// ---------------- K1b: pack Wcat into fragment-tiled bf16 -----------------
__global__ __launch_bounds__(256) void wcat_kernel(
    const float* __restrict__ W_U, const float* __restrict__ W_B,
    const float* __restrict__ W_C, const float* __restrict__ W_d1,
    unsigned short* __restrict__ wcp) {
  int g = blockIdx.x;
  int kq = blockIdx.y;
  int tid = threadIdx.x;
  int c8 = tid & 15, r = tid >> 4;
  int n = g * 16 + r;
  int k = kq * 128 + c8 * 8;
  const float* src = nullptr;
  if (n < 64)        src = W_U + (size_t)n * kD;
  else if (n < 128)  src = W_B + (size_t)(n - 64) * kD;
  else if (n < 192)  src = W_C + (size_t)(n - 128) * kD;
  else if (n < 196)  src = W_d1 + (size_t)(n - 192) * kD;
  u16x8 o;
#pragma unroll
  for (int j = 0; j < 8; ++j) o[j] = src ? f2bf_(src[k + j]) : (unsigned short)0;
  size_t dst = (size_t)g * kGT + (size_t)(k >> 5) * 512 + r * 32 + (k & 31);
  *(u16x8*)(wcp + dst) = o;
}

// ---------------- K2: raw = xcp @ wcp^T via MFMA (packed, coalesced) ------
__global__ __launch_bounds__(256) void gemm_mfma_kernel(
    const unsigned short* __restrict__ xcp,
    const unsigned short* __restrict__ wcp, float* __restrict__ raw) {
  int tid = threadIdx.x;
  int w = tid >> 6, lane = tid & 63;
  int m0 = blockIdx.x * 32 + (w >> 1) * 16;
  int n0 = blockIdx.y * 128 + (w & 1) * 64;
  int l15 = lane & 15, lk = lane >> 4;

  const unsigned short* ap =
      xcp + (size_t)(blockIdx.x * 2 + (w >> 1)) * kGT + l15 * 32 + lk * 8;
  const unsigned short* bp =
      wcp + (size_t)(blockIdx.y * 8 + (w & 1) * 4) * kGT + l15 * 32 + lk * 8;

  f32x4 acc0 = {0.f, 0.f, 0.f, 0.f}, acc1 = acc0, acc2 = acc0, acc3 = acc0;

  bf16x8 a  = *(const bf16x8*)(ap);
  bf16x8 b0 = *(const bf16x8*)(bp + (size_t)0 * kGT);
  bf16x8 b1 = *(const bf16x8*)(bp + (size_t)1 * kGT);
  bf16x8 b2 = *(const bf16x8*)(bp + (size_t)2 * kGT);
  bf16x8 b3 = *(const bf16x8*)(bp + (size_t)3 * kGT);

#pragma unroll 4
  for (int kt = 1; kt < 32; ++kt) {
    bf16x8 an  = *(const bf16x8*)(ap + kt * 512);
    bf16x8 b0n = *(const bf16x8*)(bp + (size_t)0 * kGT + kt * 512);
    bf16x8 b1n = *(const bf16x8*)(bp + (size_t)1 * kGT + kt * 512);
    bf16x8 b2n = *(const bf16x8*)(bp + (size_t)2 * kGT + kt * 512);
    bf16x8 b3n = *(const bf16x8*)(bp + (size_t)3 * kGT + kt * 512);
    acc0 = __builtin_amdgcn_mfma_f32_16x16x32_bf16(a, b0, acc0, 0, 0, 0);
    acc1 = __builtin_amdgcn_mfma_f32_16x16x32_bf16(a, b1, acc1, 0, 0, 0);
    acc2 = __builtin_amdgcn_mfma_f32_16x16x32_bf16(a, b2, acc2, 0, 0, 0);
    acc3 = __builtin_amdgcn_mfma_f32_16x16x32_bf16(a, b3, acc3, 0, 0, 0);
    a = an; b0 = b0n; b1 = b1n; b2 = b2n; b3 = b3n;
  }
  acc0 = __builtin_amdgcn_mfma_f32_16x16x32_bf16(a, b0, acc0, 0, 0, 0);
  acc1 = __builtin_amdgcn_mfma_f32_16x16x32_bf16(a, b1, acc1, 0, 0, 0);
  acc2 = __builtin_amdgcn_mfma_f32_16x16x32_bf16(a, b2, acc2, 0, 0, 0);
  acc3 = __builtin_amdgcn_mfma_f32_16x16x32_bf16(a, b3, acc3, 0, 0, 0);

  int crow0 = m0 + lk * 4;
  f32x4 accs[4] = {acc0, acc1, acc2, acc3};
#pragma unroll
  for (int nf = 0; nf < 4; ++nf) {
    int col = n0 + nf * 16 + l15;
#pragma unroll
    for (int r = 0; r < 4; ++r) {
      int row = crow0 + r;
      if (row < kM) raw[(size_t)row * kNR + col] = accs[nf][r];
    }
  }
}

// ---------------- K3: passA — delta/D, G, C~ (bf16), Bpre (bf16), dec -----
__global__ __launch_bounds__(256) void passA_kernel(
    const float* __restrict__ raw,
    const float* __restrict__ b_B, const float* __restrict__ b_C,
    const float* __restrict__ b_d1, const float* __restrict__ W_d2,
    const float* __restrict__ b_d2, const float* __restrict__ a_hat,
    unsigned short* __restrict__ Gm, unsigned short* __restrict__ Ctb,
    unsigned short* __restrict__ Bpre, float* __restrict__ dec) {
  __shared__ __align__(16) float Cfl[32][68];
  __shared__ __align__(16) float BulT[64][36];
  __shared__ float deltal[32];
  __shared__ float Dloc[32];
  __shared__ float logAl[64];

  int tid = threadIdx.x;
  int bc = blockIdx.x;
  int b = bc / kTC, c = bc % kTC;
  int t0 = c * kQ;
  int clen = min(kQ, kLc - t0);

  if (tid < 64) logAl[tid] = -expf(a_hat[tid]);
  if (tid >= 64 && tid < 96) {
    int t = tid - 64;
    float r0 = 0.f, r1 = 0.f, r2 = 0.f, r3 = 0.f;
    if (t < clen) {
      const float* rp = raw + (size_t)(b * kLc + t0 + t) * kNR + 192;
      r0 = rp[0]; r1 = rp[1]; r2 = rp[2]; r3 = rp[3];
    }
    float f0 = siluf_(r0 + b_d1[0]);
    float f1 = siluf_(r1 + b_d1[1]);
    float f2 = siluf_(r2 + b_d1[2]);
    float f3 = siluf_(r3 + b_d1[3]);
    float z = fmaf(f0, W_d2[0],
              fmaf(f1, W_d2[1], fmaf(f2, W_d2[2], fmaf(f3, W_d2[3], b_d2[0]))));
    deltal[t] = softplusf_(z);
  }
  // Bu / Cf  (pad rows -> u=0 so Bu=0)
  for (int p = 0; p < 8; ++p) {
    int idx = p * 256 + tid;
    int t = idx >> 6, s = idx & 63;
    float u = 0.f, rb = 0.f, rc = 0.f;
    if (t < clen) {
      const float* rp = raw + (size_t)(b * kLc + t0 + t) * kNR;
      u = rp[s]; rb = rp[64 + s]; rc = rp[128 + s];
    }
    BulT[s][t] = (rb + b_B[s]) * u;
    Cfl[t][s] = rc + b_C[s];
  }
  __syncthreads();
  if (tid < 32) {
    float sum = 0.f;
    for (int j = 0; j <= tid; ++j) sum += deltal[j];
    Dloc[tid] = sum;
  }
  __syncthreads();
  float Dend = Dloc[31];

  // C~ bf16 [t][s]
  for (int p = 0; p < 8; ++p) {
    int idx = p * 256 + tid;
    int t = idx >> 6, s = idx & 63;
    Ctb[(size_t)bc * 2048 + t * kS + s] =
        f2bf_(Cfl[t][s] * __expf(Dloc[t] * logAl[s]));
  }
  // Bpre bf16 [s][tau]
  for (int p = 0; p < 8; ++p) {
    int idx = p * 256 + tid;
    int s = idx >> 5, tau = idx & 31;
    Bpre[(size_t)bc * 2048 + s * kQ + tau] =
        f2bf_(BulT[s][tau] * __expf((Dend - Dloc[tau]) * logAl[s]));
  }
  if (tid < 64) dec[(size_t)bc * kS + tid] = __expf(Dend * logAl[tid]);
  // G[t][tau] lower-triangular, bf16
  for (int p = 0; p < 4; ++p) {
    int idx = p * 256 + tid;
    int t = idx >> 5, tau = idx & 31;
    float g = 0.f;
    if (tau <= t) {
      float dd = Dloc[t] - Dloc[tau];
      for (int s = 0; s < 64; ++s)
        g = fmaf(Cfl[t][s] * BulT[s][tau], __expf(dd * logAl[s]), g);
    }
    Gm[((size_t)bc * 32 + t) * kQ + tau] = f2bf_(g);
  }
}

// ---------------- K3b: ScT[d][s] = x @ Bpre^T via MFMA --------------------
__global__ __launch_bounds__(256) void scT_kernel(
    const unsigned short* __restrict__ Bpre, const unsigned short* __restrict__ xT,
    unsigned short* __restrict__ ScT) {
  __shared__ __align__(16) unsigned short Bprel[64][40];
  int tid = threadIdx.x;
  int bc = blockIdx.x;
  int dq = blockIdx.y;  // 0..3
  {
    int s = tid >> 2, c8 = (tid & 3) * 8;
    *(u16x8*)&Bprel[s][c8] = *(const u16x8*)(Bpre + (size_t)bc * 2048 + s * kQ + c8);
  }
  __syncthreads();
  int w = tid >> 6, lane = tid & 63;
  int l15 = lane & 15, lk = lane >> 4;
  bf16x8 bfr[4];
#pragma unroll
  for (int st = 0; st < 4; ++st)
    bfr[st] = *(const bf16x8*)&Bprel[st * 16 + l15][lk * 8];
  const unsigned short* xTb = xT + (size_t)bc * kD * kQ;
  unsigned short* so = ScT + (size_t)bc * kD * kS;
#pragma unroll
  for (int mt = 0; mt < 4; ++mt) {
    int d0t = dq * 256 + (w * 4 + mt) * 16;
    bf16x8 af = *(const bf16x8*)(xTb + (size_t)(d0t + l15) * kQ + lk * 8);
    f32x4 acc[4];
#pragma unroll
    for (int st = 0; st < 4; ++st) {
      f32x4 z = {0.f, 0.f, 0.f, 0.f};
      acc[st] = __builtin_amdgcn_mfma_f32_16x16x32_bf16(af, bfr[st], z, 0, 0, 0);
    }
#pragma unroll
    for (int st = 0; st < 4; ++st)
#pragma unroll
      for (int r = 0; r < 4; ++r)
        so[(size_t)(d0t + lk * 4 + r) * kS + st * 16 + l15] = f2bf_(acc[st][r]);
  }
}

// ---------------- K4: cross-chunk scan on ScT (flat, burst-prefetched) ----
__global__ __launch_bounds__(256) void chscan_kernel(
    const float* __restrict__ dec, unsigned short* __restrict__ Sc) {
  int bk = blockIdx.x >> 7;           // batch
  int part = blockIdx.x & 127;
  int p = part * 256 + threadIdx.x;   // pair index over kS*kD/2
  int flat = p * 2;                   // element index (d*64 + s), s0 even
  int s0 = flat & 63;
  const size_t cstride = (size_t)kS * kD;
  size_t base = (size_t)bk * kTC * cstride + flat;
  const float* decb = dec + (size_t)bk * kTC * kS + s0;
  float r0 = 0.f, r1 = 0.f;
  for (int c0 = 0; c0 < kTC; c0 += 16) {
    int n = kTC - c0;
    if (n > 16) n = 16;
    unsigned v[16];
    float2 dd[16];
#pragma unroll
    for (int j = 0; j < 16; ++j) {
      if (j < n) {
        v[j] = *(const unsigned*)(Sc + base + (size_t)(c0 + j) * cstride);
        dd[j] = *(const float2*)(decb + (size_t)(c0 + j) * kS);
      }
    }
#pragma unroll
    for (int j = 0; j < 16; ++j) {
      if (j < n) {
        unsigned ost = (unsigned)f2bf_(r0) | ((unsigned)f2bf_(r1) << 16);
        *(unsigned*)(Sc + base + (size_t)(c0 + j) * cstride) = ost;  // H_before
        r0 = fmaf(dd[j].x, r0, bf2f_((unsigned short)(v[j] & 0xFFFF)));
        r1 = fmaf(dd[j].y, r1, bf2f_((unsigned short)(v[j] >> 16)));
      }
    }
  }
}

// ---------------- K5: passB — y = G@x + C~@H0 + ds*x, all-MFMA ------------
__global__ __launch_bounds__(256) void passB_kernel(
    const unsigned short* __restrict__ Gm, const unsigned short* __restrict__ Ctb,
    const unsigned short* __restrict__ xT, const unsigned short* __restrict__ hT,
    const float* __restrict__ D_skip, float* __restrict__ out) {
  int tid = threadIdx.x;
  int bc = blockIdx.x;
  int quarter = blockIdx.y;
  int b = bc / kTC, c = bc % kTC;
  int t0c = c * kQ;
  int clen = min(kQ, kLc - t0c);
  int w = tid >> 6, lane = tid & 63;
  int l15 = lane & 15, lk = lane >> 4;

  const unsigned short* Gb = Gm + (size_t)bc * 32 * kQ;
  bf16x8 aG0 = *(const bf16x8*)(Gb + (size_t)l15 * kQ + lk * 8);
  bf16x8 aG1 = *(const bf16x8*)(Gb + (size_t)(16 + l15) * kQ + lk * 8);
  const unsigned short* Cb = Ctb + (size_t)bc * 2048;
  bf16x8 aC0l = *(const bf16x8*)(Cb + (size_t)l15 * kS + lk * 8);
  bf16x8 aC0h = *(const bf16x8*)(Cb + (size_t)l15 * kS + 32 + lk * 8);
  bf16x8 aC1l = *(const bf16x8*)(Cb + (size_t)(16 + l15) * kS + lk * 8);
  bf16x8 aC1h = *(const bf16x8*)(Cb + (size_t)(16 + l15) * kS + 32 + lk * 8);

  const unsigned short* xTb = xT + (size_t)bc * kD * kQ;
  const unsigned short* hTb = hT + (size_t)bc * kD * kS;
  size_t rowbase = (size_t)b * kLc + t0c;
  int dbase = quarter * 256 + w * 64;

#pragma unroll
  for (int nt = 0; nt < 4; ++nt) {
    int d = dbase + nt * 16 + l15;
    bf16x8 bX  = *(const bf16x8*)(xTb + (size_t)d * kQ + lk * 8);
    bf16x8 bHl = *(const bf16x8*)(hTb + (size_t)d * kS + lk * 8);
    bf16x8 bHh = *(const bf16x8*)(hTb + (size_t)d * kS + 32 + lk * 8);
    f32x4 z = {0.f, 0.f, 0.f, 0.f};
    f32x4 accA = __builtin_amdgcn_mfma_f32_16x16x32_bf16(aC0l, bHl, z, 0, 0, 0);
    accA = __builtin_amdgcn_mfma_f32_16x16x32_bf16(aC0h, bHh, accA, 0, 0, 0);
    accA = __builtin_amdgcn_mfma_f32_16x16x32_bf16(aG0, bX, accA, 0, 0, 0);
    f32x4 accB = __builtin_amdgcn_mfma_f32_16x16x32_bf16(aC1l, bHl, z, 0, 0, 0);
    accB = __builtin_amdgcn_mfma_f32_16x16x32_bf16(aC1h, bHh, accB, 0, 0, 0);
    accB = __builtin_amdgcn_mfma_f32_16x16x32_bf16(aG1, bX, accB, 0, 0, 0);

    float ds = D_skip[d];
    ushort4 xa = *(const ushort4*)(xTb + (size_t)d * kQ + lk * 4);
    ushort4 xb = *(const ushort4*)(xTb + (size_t)d * kQ + 16 + lk * 4);
    const unsigned short* xap = (const unsigned short*)&xa;
    const unsigned short* xbp = (const unsigned short*)&xb;
#pragma unroll
    for (int r = 0; r < 4; ++r) {
      int t = lk * 4 + r;
      if (t < clen)
        out[(rowbase + t) * kD + d] = fmaf(ds, bf2f_(xap[r]), accA[r]);
      int t2 = 16 + lk * 4 + r;
      if (t2 < clen)
        out[(rowbase + t2) * kD + d] = fmaf(ds, bf2f_(xbp[r]), accB[r]);
    }
  }
}

extern "C" void kernel_launch(void* const* d_in, const int* in_sizes, int n_in,
                              void* d_out, int out_size, void* d_ws, size_t ws_size,
                              hipStream_t stream) {
  const float* x      = (const float*)d_in[0];
  const float* a_hat  = (const float*)d_in[1];
  const float* W_U    = (const float*)d_in[2];
  const float* W_B    = (const float*)d_in[3];
  const float* b_B    = (const float*)d_in[4];
  const float* W_C    = (const float*)d_in[5];
  const float* b_C    = (const float*)d_in[6];
  const float* W_d1   = (const float*)d_in[7];
  const float* b_d1   = (const float*)d_in[8];
  const float* W_d2   = (const float*)d_in[9];
  const float* b_d2   = (const float*)d_in[10];
  const float* D_skip = (const float*)d_in[11];
  const float* conv_w = (const float*)d_in[12];
  const float* conv_b = (const float*)d_in[13];
  float* out = (float*)d_out;

  char* w = (char*)d_ws;
  auto nextp = [&](size_t bytes) {
    char* p = w;
    w += (bytes + 255) & ~(size_t)255;
    return p;
  };
  unsigned short* xcp  = (unsigned short*)nextp((size_t)kGA * kGT * 2);
  unsigned short* wcp  = (unsigned short*)nextp((size_t)16 * kGT * 2);
  unsigned short* xT   = (unsigned short*)nextp((size_t)kB * kTC * kD * kQ * 2);
  float*          raw  = (float*)nextp((size_t)kM * kNR * 4);
  unsigned short* Gm   = (unsigned short*)nextp((size_t)kB * kTC * 32 * kQ * 2);
  unsigned short* Ctb  = (unsigned short*)nextp((size_t)kB * kTC * 2048 * 2);
  unsigned short* Bpre = (unsigned short*)nextp((size_t)kB * kTC * 2048 * 2);
  float*          dec  = (float*)nextp((size_t)kB * kTC * kS * 4);
  unsigned short* ScT  = (unsigned short*)nextp((size_t)kB * kTC * kD * kS * 2);

  // zero-pad xcp groups 512..513 (rows >= kM); conv overwrites valid rows
  hipMemsetAsync(xcp + (size_t)512 * kGT, 0, (size_t)2 * kGT * 2, stream);

  dim3 cgrid(kB * kTC, kD / 128);
  conv_kernel<<<cgrid, 256, 0, stream>>>(x, conv_w, conv_b, xcp, xT);

  dim3 wgrid(16, 8);
  wcat_kernel<<<wgrid, 256, 0, stream>>>(W_U, W_B, W_C, W_d1, wcp);

  dim3 ggrid((kM + 31) / 32, 2);
  gemm_mfma_kernel<<<ggrid, 256, 0, stream>>>(xcp, wcp, raw);

  passA_kernel<<<kB * kTC, 256, 0, stream>>>(
      raw, b_B, b_C, b_d1, W_d2, b_d2, a_hat, Gm, Ctb, Bpre, dec);

  dim3 sgrid(kB * kTC, 4);
  scT_kernel<<<sgrid, 256, 0, stream>>>(Bpre, xT, ScT);

  chscan_kernel<<<kB * 128, 256, 0, stream>>>(dec, ScT);

  dim3 bgrid(kB * kTC, 4);
  passB_kernel<<<bgrid, 256, 0, stream>>>(Gm, Ctb, xT, ScT, D_skip, out);
}

// Round 13
// 111.128 us; speedup vs baseline: 1.5162x; 1.0221x over previous
//
#include <hip/hip_runtime.h>
#include <hip/hip_bf16.h>

namespace {
constexpr int kB   = 4;
constexpr int kL   = 2048;
constexpr int kLc  = 2051;   // L + 3
constexpr int kD   = 1024;
constexpr int kS   = 64;
constexpr int kM   = kB * kLc;  // 8204
constexpr int kNR  = 256;       // raw row stride (196 real cols)
constexpr int kQ   = 32;        // chunk length
constexpr int kTC  = (kLc + kQ - 1) / kQ;  // 65 chunks per batch
constexpr int kGA  = 514;       // A groups of 16 rows (8224 padded rows)
constexpr int kGT  = 16384;     // u16 per 16-row group (16*1024)
}

typedef __attribute__((ext_vector_type(8))) short bf16x8;
typedef __attribute__((ext_vector_type(4))) float f32x4;
typedef __attribute__((ext_vector_type(8))) unsigned short u16x8;

__device__ __forceinline__ float siluf_(float v) {
  return v / (1.f + expf(-v));
}
__device__ __forceinline__ float softplusf_(float v) {
  return (v > 20.f) ? v : log1pf(expf(v));
}
__device__ __forceinline__ unsigned short f2bf_(float f) {
  unsigned u = __float_as_uint(f);
  unsigned r = u + 0x7FFF + ((u >> 16) & 1);
  return (unsigned short)(r >> 16);
}
__device__ __forceinline__ float bf2f_(unsigned short u) {
  return __uint_as_float(((unsigned)u) << 16);
}

// ---------------- K1b (FIRST): pack Wcat bf16 + zero xcp pad groups -------
// Runs BEFORE conv so conv's valid rows in group 512 overwrite the zeros.
__global__ __launch_bounds__(256) void wcat_kernel(
    const float* __restrict__ W_U, const float* __restrict__ W_B,
    const float* __restrict__ W_C, const float* __restrict__ W_d1,
    unsigned short* __restrict__ wcp, unsigned short* __restrict__ xcp) {
  int g = blockIdx.x;
  int kq = blockIdx.y;
  int tid = threadIdx.x;
  int c8 = tid & 15, r = tid >> 4;
  int n = g * 16 + r;
  int k = kq * 128 + c8 * 8;
  const float* src = nullptr;
  if (n < 64)        src = W_U + (size_t)n * kD;
  else if (n < 128)  src = W_B + (size_t)(n - 64) * kD;
  else if (n < 192)  src = W_C + (size_t)(n - 128) * kD;
  else if (n < 196)  src = W_d1 + (size_t)(n - 192) * kD;
  u16x8 o;
#pragma unroll
  for (int j = 0; j < 8; ++j) o[j] = src ? f2bf_(src[k + j]) : (unsigned short)0;
  size_t dst = (size_t)g * kGT + (size_t)(k >> 5) * 512 + r * 32 + (k & 31);
  *(u16x8*)(wcp + dst) = o;
  // zero the xcp pad groups 512..513 (2*kGT u16 total); conv then overwrites
  // the valid rows (8192..8203) afterwards.
  if (kq == 0) {
    u16x8 z = {0, 0, 0, 0, 0, 0, 0, 0};
    size_t off = (size_t)512 * kGT + ((size_t)g * 256 + tid) * 8;
    *(u16x8*)(xcp + off) = z;
  }
}

// ---------------- K1: conv1d tile kernel -> xcp (packed) + xT (LDS xpose) -
__global__ __launch_bounds__(256) void conv_kernel(
    const float* __restrict__ x, const float* __restrict__ cw,
    const float* __restrict__ cb, unsigned short* __restrict__ xcp,
    unsigned short* __restrict__ xT) {
  __shared__ unsigned short tileT[kQ][136];  // [tau][d], pad->4-way max

  int tid = threadIdx.x;
  int bc = blockIdx.x;
  int d0 = blockIdx.y * 128;
  int b = bc / kTC, c = bc % kTC;
  int t0 = c * kQ;
  int dl = tid & 127, tg = tid >> 7;
  int d = d0 + dl;

  float4 wv = *(const float4*)(cw + (size_t)d * 4);
  float bias = cb[d];
  int tstart = t0 + tg * 16;

  const float* xb = x + (size_t)b * kL * kD + d;
  auto ldx = [&](int t) -> float {
    return (t >= 0 && t < kL) ? xb[(size_t)t * kD] : 0.f;
  };
  float xm3 = ldx(tstart - 3);
  float xm2 = ldx(tstart - 2);
  float xm1 = ldx(tstart - 1);

  unsigned short vals[16];
#pragma unroll
  for (int j = 0; j < 16; ++j) {
    int t = tstart + j;
    float x0 = ldx(t);
    float o = bias + wv.x * xm3 + wv.y * xm2 + wv.z * xm1 + wv.w * x0;
    vals[j] = (t < kLc) ? f2bf_(o) : (unsigned short)0;
    tileT[tg * 16 + j][dl] = vals[j];
    xm3 = xm2; xm2 = xm1; xm1 = x0;
  }
  // xcp store from registers: lanes fill whole 64B lines (dense)
#pragma unroll
  for (int j = 0; j < 16; ++j) {
    int t = tstart + j;
    if (t < kLc) {
      int bt = b * kLc + t;
      size_t po = (size_t)(bt >> 4) * kGT + (size_t)(d >> 5) * 512 +
                  (size_t)(bt & 15) * 32 + (d & 31);
      xcp[po] = vals[j];
    }
  }
  __syncthreads();
  // xT store: [bc][d][tau], contiguous 32B per (d, tau-half)
  {
    int d_l = tid >> 1, th = tid & 1;
    u16x8 o0, o1;
#pragma unroll
    for (int j = 0; j < 8; ++j) {
      o0[j] = tileT[th * 16 + j][d_l];
      o1[j] = tileT[th * 16 + 8 + j][d_l];
    }
    unsigned short* dst = xT + ((size_t)bc * kD + d0 + d_l) * kQ + th * 16;
    *(u16x8*)dst = o0;
    *(u16x8*)(dst + 8) = o1;
  }
}

// ---------------- K2: raw = xcp @ wcp^T via MFMA (packed, coalesced) ------
__global__ __launch_bounds__(256) void gemm_mfma_kernel(
    const unsigned short* __restrict__ xcp,
    const unsigned short* __restrict__ wcp, float* __restrict__ raw) {
  int tid = threadIdx.x;
  int w = tid >> 6, lane = tid & 63;
  int m0 = blockIdx.x * 32 + (w >> 1) * 16;
  int n0 = blockIdx.y * 128 + (w & 1) * 64;
  int l15 = lane & 15, lk = lane >> 4;

  const unsigned short* ap =
      xcp + (size_t)(blockIdx.x * 2 + (w >> 1)) * kGT + l15 * 32 + lk * 8;
  const unsigned short* bp =
      wcp + (size_t)(blockIdx.y * 8 + (w & 1) * 4) * kGT + l15 * 32 + lk * 8;

  f32x4 acc0 = {0.f, 0.f, 0.f, 0.f}, acc1 = acc0, acc2 = acc0, acc3 = acc0;

  bf16x8 a  = *(const bf16x8*)(ap);
  bf16x8 b0 = *(const bf16x8*)(bp + (size_t)0 * kGT);
  bf16x8 b1 = *(const bf16x8*)(bp + (size_t)1 * kGT);
  bf16x8 b2 = *(const bf16x8*)(bp + (size_t)2 * kGT);
  bf16x8 b3 = *(const bf16x8*)(bp + (size_t)3 * kGT);

#pragma unroll 4
  for (int kt = 1; kt < 32; ++kt) {
    bf16x8 an  = *(const bf16x8*)(ap + kt * 512);
    bf16x8 b0n = *(const bf16x8*)(bp + (size_t)0 * kGT + kt * 512);
    bf16x8 b1n = *(const bf16x8*)(bp + (size_t)1 * kGT + kt * 512);
    bf16x8 b2n = *(const bf16x8*)(bp + (size_t)2 * kGT + kt * 512);
    bf16x8 b3n = *(const bf16x8*)(bp + (size_t)3 * kGT + kt * 512);
    acc0 = __builtin_amdgcn_mfma_f32_16x16x32_bf16(a, b0, acc0, 0, 0, 0);
    acc1 = __builtin_amdgcn_mfma_f32_16x16x32_bf16(a, b1, acc1, 0, 0, 0);
    acc2 = __builtin_amdgcn_mfma_f32_16x16x32_bf16(a, b2, acc2, 0, 0, 0);
    acc3 = __builtin_amdgcn_mfma_f32_16x16x32_bf16(a, b3, acc3, 0, 0, 0);
    a = an; b0 = b0n; b1 = b1n; b2 = b2n; b3 = b3n;
  }
  acc0 = __builtin_amdgcn_mfma_f32_16x16x32_bf16(a, b0, acc0, 0, 0, 0);
  acc1 = __builtin_amdgcn_mfma_f32_16x16x32_bf16(a, b1, acc1, 0, 0, 0);
  acc2 = __builtin_amdgcn_mfma_f32_16x16x32_bf16(a, b2, acc2, 0, 0, 0);
  acc3 = __builtin_amdgcn_mfma_f32_16x16x32_bf16(a, b3, acc3, 0, 0, 0);

  int crow0 = m0 + lk * 4;
  f32x4 accs[4] = {acc0, acc1, acc2, acc3};
#pragma unroll
  for (int nf = 0; nf < 4; ++nf) {
    int col = n0 + nf * 16 + l15;
#pragma unroll
    for (int r = 0; r < 4; ++r) {
      int row = crow0 + r;
      if (row < kM) raw[(size_t)row * kNR + col] = accs[nf][r];
    }
  }
}

// ---------------- K3: passA — delta/D, G, C~ (bf16), Bpre (bf16), dec -----
__global__ __launch_bounds__(256) void passA_kernel(
    const float* __restrict__ raw,
    const float* __restrict__ b_B, const float* __restrict__ b_C,
    const float* __restrict__ b_d1, const float* __restrict__ W_d2,
    const float* __restrict__ b_d2, const float* __restrict__ a_hat,
    unsigned short* __restrict__ Gm, unsigned short* __restrict__ Ctb,
    unsigned short* __restrict__ Bpre, float* __restrict__ dec) {
  __shared__ __align__(16) float Cfl[32][68];
  __shared__ __align__(16) float BulT[64][36];
  __shared__ float deltal[32];
  __shared__ float Dloc[32];
  __shared__ float logAl[64];

  int tid = threadIdx.x;
  int bc = blockIdx.x;
  int b = bc / kTC, c = bc % kTC;
  int t0 = c * kQ;
  int clen = min(kQ, kLc - t0);

  if (tid < 64) logAl[tid] = -expf(a_hat[tid]);
  if (tid >= 64 && tid < 96) {
    int t = tid - 64;
    float r0 = 0.f, r1 = 0.f, r2 = 0.f, r3 = 0.f;
    if (t < clen) {
      const float* rp = raw + (size_t)(b * kLc + t0 + t) * kNR + 192;
      r0 = rp[0]; r1 = rp[1]; r2 = rp[2]; r3 = rp[3];
    }
    float f0 = siluf_(r0 + b_d1[0]);
    float f1 = siluf_(r1 + b_d1[1]);
    float f2 = siluf_(r2 + b_d1[2]);
    float f3 = siluf_(r3 + b_d1[3]);
    float z = fmaf(f0, W_d2[0],
              fmaf(f1, W_d2[1], fmaf(f2, W_d2[2], fmaf(f3, W_d2[3], b_d2[0]))));
    deltal[t] = softplusf_(z);
  }
  // Bu / Cf  (pad rows -> u=0 so Bu=0)
  for (int p = 0; p < 8; ++p) {
    int idx = p * 256 + tid;
    int t = idx >> 6, s = idx & 63;
    float u = 0.f, rb = 0.f, rc = 0.f;
    if (t < clen) {
      const float* rp = raw + (size_t)(b * kLc + t0 + t) * kNR;
      u = rp[s]; rb = rp[64 + s]; rc = rp[128 + s];
    }
    BulT[s][t] = (rb + b_B[s]) * u;
    Cfl[t][s] = rc + b_C[s];
  }
  __syncthreads();
  if (tid < 32) {
    float sum = 0.f;
    for (int j = 0; j <= tid; ++j) sum += deltal[j];
    Dloc[tid] = sum;
  }
  __syncthreads();
  float Dend = Dloc[31];

  // C~ bf16 [t][s]
  for (int p = 0; p < 8; ++p) {
    int idx = p * 256 + tid;
    int t = idx >> 6, s = idx & 63;
    Ctb[(size_t)bc * 2048 + t * kS + s] =
        f2bf_(Cfl[t][s] * __expf(Dloc[t] * logAl[s]));
  }
  // Bpre bf16 [s][tau]
  for (int p = 0; p < 8; ++p) {
    int idx = p * 256 + tid;
    int s = idx >> 5, tau = idx & 31;
    Bpre[(size_t)bc * 2048 + s * kQ + tau] =
        f2bf_(BulT[s][tau] * __expf((Dend - Dloc[tau]) * logAl[s]));
  }
  if (tid < 64) dec[(size_t)bc * kS + tid] = __expf(Dend * logAl[tid]);
  // G[t][tau] lower-triangular, bf16
  for (int p = 0; p < 4; ++p) {
    int idx = p * 256 + tid;
    int t = idx >> 5, tau = idx & 31;
    float g = 0.f;
    if (tau <= t) {
      float dd = Dloc[t] - Dloc[tau];
      for (int s = 0; s < 64; ++s)
        g = fmaf(Cfl[t][s] * BulT[s][tau], __expf(dd * logAl[s]), g);
    }
    Gm[((size_t)bc * 32 + t) * kQ + tau] = f2bf_(g);
  }
}

// ---------------- K3b: ScT[d][s] = x @ Bpre^T via MFMA --------------------
__global__ __launch_bounds__(256) void scT_kernel(
    const unsigned short* __restrict__ Bpre, const unsigned short* __restrict__ xT,
    unsigned short* __restrict__ ScT) {
  __shared__ __align__(16) unsigned short Bprel[64][40];
  int tid = threadIdx.x;
  int bc = blockIdx.x;
  int dq = blockIdx.y;  // 0..3
  {
    int s = tid >> 2, c8 = (tid & 3) * 8;
    *(u16x8*)&Bprel[s][c8] = *(const u16x8*)(Bpre + (size_t)bc * 2048 + s * kQ + c8);
  }
  __syncthreads();
  int w = tid >> 6, lane = tid & 63;
  int l15 = lane & 15, lk = lane >> 4;
  bf16x8 bfr[4];
#pragma unroll
  for (int st = 0; st < 4; ++st)
    bfr[st] = *(const bf16x8*)&Bprel[st * 16 + l15][lk * 8];
  const unsigned short* xTb = xT + (size_t)bc * kD * kQ;
  unsigned short* so = ScT + (size_t)bc * kD * kS;
#pragma unroll
  for (int mt = 0; mt < 4; ++mt) {
    int d0t = dq * 256 + (w * 4 + mt) * 16;
    bf16x8 af = *(const bf16x8*)(xTb + (size_t)(d0t + l15) * kQ + lk * 8);
    f32x4 acc[4];
#pragma unroll
    for (int st = 0; st < 4; ++st) {
      f32x4 z = {0.f, 0.f, 0.f, 0.f};
      acc[st] = __builtin_amdgcn_mfma_f32_16x16x32_bf16(af, bfr[st], z, 0, 0, 0);
    }
#pragma unroll
    for (int st = 0; st < 4; ++st)
#pragma unroll
      for (int r = 0; r < 4; ++r)
        so[(size_t)(d0t + lk * 4 + r) * kS + st * 16 + l15] = f2bf_(acc[st][r]);
  }
}

// ---------------- K4: cross-chunk scan on ScT (flat, burst-prefetched) ----
__global__ __launch_bounds__(256) void chscan_kernel(
    const float* __restrict__ dec, unsigned short* __restrict__ Sc) {
  int bk = blockIdx.x >> 7;           // batch
  int part = blockIdx.x & 127;
  int p = part * 256 + threadIdx.x;   // pair index over kS*kD/2
  int flat = p * 2;                   // element index (d*64 + s), s0 even
  int s0 = flat & 63;
  const size_t cstride = (size_t)kS * kD;
  size_t base = (size_t)bk * kTC * cstride + flat;
  const float* decb = dec + (size_t)bk * kTC * kS + s0;
  float r0 = 0.f, r1 = 0.f;
  for (int c0 = 0; c0 < kTC; c0 += 16) {
    int n = kTC - c0;
    if (n > 16) n = 16;
    unsigned v[16];
    float2 dd[16];
#pragma unroll
    for (int j = 0; j < 16; ++j) {
      if (j < n) {
        v[j] = *(const unsigned*)(Sc + base + (size_t)(c0 + j) * cstride);
        dd[j] = *(const float2*)(decb + (size_t)(c0 + j) * kS);
      }
    }
#pragma unroll
    for (int j = 0; j < 16; ++j) {
      if (j < n) {
        unsigned ost = (unsigned)f2bf_(r0) | ((unsigned)f2bf_(r1) << 16);
        *(unsigned*)(Sc + base + (size_t)(c0 + j) * cstride) = ost;  // H_before
        r0 = fmaf(dd[j].x, r0, bf2f_((unsigned short)(v[j] & 0xFFFF)));
        r1 = fmaf(dd[j].y, r1, bf2f_((unsigned short)(v[j] >> 16)));
      }
    }
  }
}

// ---------------- K5: passB — y = G@x + C~@H0 + ds*x, all-MFMA ------------
__global__ __launch_bounds__(256) void passB_kernel(
    const unsigned short* __restrict__ Gm, const unsigned short* __restrict__ Ctb,
    const unsigned short* __restrict__ xT, const unsigned short* __restrict__ hT,
    const float* __restrict__ D_skip, float* __restrict__ out) {
  int tid = threadIdx.x;
  int bc = blockIdx.x;
  int quarter = blockIdx.y;
  int b = bc / kTC, c = bc % kTC;
  int t0c = c * kQ;
  int clen = min(kQ, kLc - t0c);
  int w = tid >> 6, lane = tid & 63;
  int l15 = lane & 15, lk = lane >> 4;

  const unsigned short* Gb = Gm + (size_t)bc * 32 * kQ;
  bf16x8 aG0 = *(const bf16x8*)(Gb + (size_t)l15 * kQ + lk * 8);
  bf16x8 aG1 = *(const bf16x8*)(Gb + (size_t)(16 + l15) * kQ + lk * 8);
  const unsigned short* Cb = Ctb + (size_t)bc * 2048;
  bf16x8 aC0l = *(const bf16x8*)(Cb + (size_t)l15 * kS + lk * 8);
  bf16x8 aC0h = *(const bf16x8*)(Cb + (size_t)l15 * kS + 32 + lk * 8);
  bf16x8 aC1l = *(const bf16x8*)(Cb + (size_t)(16 + l15) * kS + lk * 8);
  bf16x8 aC1h = *(const bf16x8*)(Cb + (size_t)(16 + l15) * kS + 32 + lk * 8);

  const unsigned short* xTb = xT + (size_t)bc * kD * kQ;
  const unsigned short* hTb = hT + (size_t)bc * kD * kS;
  size_t rowbase = (size_t)b * kLc + t0c;
  int dbase = quarter * 256 + w * 64;

#pragma unroll
  for (int nt = 0; nt < 4; ++nt) {
    int d = dbase + nt * 16 + l15;
    bf16x8 bX  = *(const bf16x8*)(xTb + (size_t)d * kQ + lk * 8);
    bf16x8 bHl = *(const bf16x8*)(hTb + (size_t)d * kS + lk * 8);
    bf16x8 bHh = *(const bf16x8*)(hTb + (size_t)d * kS + 32 + lk * 8);
    f32x4 z = {0.f, 0.f, 0.f, 0.f};
    f32x4 accA = __builtin_amdgcn_mfma_f32_16x16x32_bf16(aC0l, bHl, z, 0, 0, 0);
    accA = __builtin_amdgcn_mfma_f32_16x16x32_bf16(aC0h, bHh, accA, 0, 0, 0);
    accA = __builtin_amdgcn_mfma_f32_16x16x32_bf16(aG0, bX, accA, 0, 0, 0);
    f32x4 accB = __builtin_amdgcn_mfma_f32_16x16x32_bf16(aC1l, bHl, z, 0, 0, 0);
    accB = __builtin_amdgcn_mfma_f32_16x16x32_bf16(aC1h, bHh, accB, 0, 0, 0);
    accB = __builtin_amdgcn_mfma_f32_16x16x32_bf16(aG1, bX, accB, 0, 0, 0);

    float ds = D_skip[d];
    ushort4 xa = *(const ushort4*)(xTb + (size_t)d * kQ + lk * 4);
    ushort4 xb = *(const ushort4*)(xTb + (size_t)d * kQ + 16 + lk * 4);
    const unsigned short* xap = (const unsigned short*)&xa;
    const unsigned short* xbp = (const unsigned short*)&xb;
#pragma unroll
    for (int r = 0; r < 4; ++r) {
      int t = lk * 4 + r;
      if (t < clen)
        out[(rowbase + t) * kD + d] = fmaf(ds, bf2f_(xap[r]), accA[r]);
      int t2 = 16 + lk * 4 + r;
      if (t2 < clen)
        out[(rowbase + t2) * kD + d] = fmaf(ds, bf2f_(xbp[r]), accB[r]);
    }
  }
}

extern "C" void kernel_launch(void* const* d_in, const int* in_sizes, int n_in,
                              void* d_out, int out_size, void* d_ws, size_t ws_size,
                              hipStream_t stream) {
  const float* x      = (const float*)d_in[0];
  const float* a_hat  = (const float*)d_in[1];
  const float* W_U    = (const float*)d_in[2];
  const float* W_B    = (const float*)d_in[3];
  const float* b_B    = (const float*)d_in[4];
  const float* W_C    = (const float*)d_in[5];
  const float* b_C    = (const float*)d_in[6];
  const float* W_d1   = (const float*)d_in[7];
  const float* b_d1   = (const float*)d_in[8];
  const float* W_d2   = (const float*)d_in[9];
  const float* b_d2   = (const float*)d_in[10];
  const float* D_skip = (const float*)d_in[11];
  const float* conv_w = (const float*)d_in[12];
  const float* conv_b = (const float*)d_in[13];
  float* out = (float*)d_out;

  char* w = (char*)d_ws;
  auto nextp = [&](size_t bytes) {
    char* p = w;
    w += (bytes + 255) & ~(size_t)255;
    return p;
  };
  unsigned short* xcp  = (unsigned short*)nextp((size_t)kGA * kGT * 2);
  unsigned short* wcp  = (unsigned short*)nextp((size_t)16 * kGT * 2);
  unsigned short* xT   = (unsigned short*)nextp((size_t)kB * kTC * kD * kQ * 2);
  float*          raw  = (float*)nextp((size_t)kM * kNR * 4);
  unsigned short* Gm   = (unsigned short*)nextp((size_t)kB * kTC * 32 * kQ * 2);
  unsigned short* Ctb  = (unsigned short*)nextp((size_t)kB * kTC * 2048 * 2);
  unsigned short* Bpre = (unsigned short*)nextp((size_t)kB * kTC * 2048 * 2);
  float*          dec  = (float*)nextp((size_t)kB * kTC * kS * 4);
  unsigned short* ScT  = (unsigned short*)nextp((size_t)kB * kTC * kD * kS * 2);

  // wcat FIRST: zeroes xcp pad groups before conv writes valid rows there.
  dim3 wgrid(16, 8);
  wcat_kernel<<<wgrid, 256, 0, stream>>>(W_U, W_B, W_C, W_d1, wcp, xcp);

  dim3 cgrid(kB * kTC, kD / 128);
  conv_kernel<<<cgrid, 256, 0, stream>>>(x, conv_w, conv_b, xcp, xT);

  dim3 ggrid((kM + 31) / 32, 2);
  gemm_mfma_kernel<<<ggrid, 256, 0, stream>>>(xcp, wcp, raw);

  passA_kernel<<<kB * kTC, 256, 0, stream>>>(
      raw, b_B, b_C, b_d1, W_d2, b_d2, a_hat, Gm, Ctb, Bpre, dec);

  dim3 sgrid(kB * kTC, 4);
  scT_kernel<<<sgrid, 256, 0, stream>>>(Bpre, xT, ScT);

  chscan_kernel<<<kB * 128, 256, 0, stream>>>(dec, ScT);

  dim3 bgrid(kB * kTC, 4);
  passB_kernel<<<bgrid, 256, 0, stream>>>(Gm, Ctb, xT, ScT, D_skip, out);
}